// Round 7
// baseline (345.511 us; speedup 1.0000x reference)
//
#include <hip/hip_runtime.h>
#include <math.h>

#define TPB 256

#define LOG2E_F 1.4426950408889634f
#define LN2_F   0.6931471805599453f

__device__ __forceinline__ float sigmoidf_(float x){
    return 1.0f / (1.0f + expf(-x));
}

// HW-transcendental BCE (continuous loss path only)
__device__ __forceinline__ float bce_fast(float x, float t){
    // max(x,0) - x*t + ln(1+exp(-|x|))
    float u = __builtin_amdgcn_exp2f(-fabsf(x) * LOG2E_F);
    return fmaxf(x, 0.0f) - x * t + LN2_F * __builtin_amdgcn_logf(1.0f + u);
}

// IoU between box a (cx,cy,w,h) and box b (cx,cy,w,h) — mirrors _pairwise_iou.
__device__ float iou_fn(float ax, float ay, float aw, float ah,
                        float bx, float by, float bw, float bh){
#pragma clang fp contract(off)
    float tlx = fmaxf(ax - aw * 0.5f, bx - bw * 0.5f);
    float tly = fmaxf(ay - ah * 0.5f, by - bh * 0.5f);
    float brx = fminf(ax + aw * 0.5f, bx + bw * 0.5f);
    float bry = fminf(ay + ah * 0.5f, by + bh * 0.5f);
    float area_a = aw * ah;
    float area_b = bw * bh;
    bool  en = (tlx < brx) && (tly < bry);
    float area_i = en ? (brx - tlx) * (bry - tly) : 0.0f;
    return area_i / (area_a + area_b - area_i + 1e-16f);
}

// Full cost(m, a). MUST be bitwise-identical between assign (selection) and
// finalize (argmin conflict resolution) — hence contract(off) and shared code.
__device__ float cost_eval(float ox, float oy, float ow, float oh,
                           float clslogit, float so, float S1,
                           float xcv, float ycv, float rad,
                           float gx, float gy, float gw, float gh,
                           bool valid, bool fgflag){
#pragma clang fp contract(off)
    if (!(valid && fgflag)) return 1e9f;   // BIG
    float raw = iou_fn(gx, gy, gw, gh, ox, oy, ow, oh);
    bool inb = (xcv > gx - 0.5f * gw) && (gx + 0.5f * gw > xcv) &&
               (ycv > gy - 0.5f * gh) && (gy + 0.5f * gh > ycv);
    bool inc = (xcv > gx - rad) && (xcv < gx + rad) &&
               (ycv > gy - rad) && (ycv < gy + rad);
    bool in_both = inb && inc;
    float pt = sqrtf(sigmoidf_(clslogit) * so);
    float logp = fmaxf(logf(pt), -100.0f);
    float l1mp = fmaxf(log1pf(-pt), -100.0f);
    float cls_cost = -(logp + S1 - l1mp);
    return cls_cost + 3.0f * (-logf(raw + 1e-8f)) + (in_both ? 0.0f : 100000.0f);
}

// ---------------- kernel 1: per-anchor precompute ----------------
// Phase A (wave-cooperative, coalesced): one wave processes one row at a time;
// lane i reads row[i] (+ lanes 0..20 read row[64+i]); per-class transcendental
// terms computed per-lane, s1/b0 reduced via shfl_xor tree. Every byte of
// `outputs` is consumed by the instruction that fetches it -> no HBM re-fetch.
// Phase B (per-thread): anchor geometry, amg/firstm init, fg flag M-scan.
__global__ __launch_bounds__(TPB) void precompute_kernel(
    const float* __restrict__ outputs, const float* __restrict__ xs,
    const float* __restrict__ ys, const float* __restrict__ st,
    const float* __restrict__ labels,
    float* __restrict__ S1mp, float* __restrict__ sobj, float* __restrict__ obj4,
    float* __restrict__ bce0, float4* __restrict__ bb4,
    unsigned char* __restrict__ fgbuf,
    int* __restrict__ amg, unsigned int* __restrict__ firstm,
    float4* __restrict__ anc4,
    int A, int M, int C, int B, int nbA)
{
    __shared__ float slab[64 * 5];
    int t = threadIdx.x;
    int b = blockIdx.x / nbA;
    int chunk = blockIdx.x - b * nbA;
    int a0 = chunk * TPB;
    int Ms = M < 64 ? M : 64;
    for (int i = t; i < Ms * 5; i += TPB) slab[i] = labels[(size_t)b * M * 5 + i];

    // ---- phase A: wave-cooperative rows ----
    int lane = t & 63, wid = t >> 6;
    int rbase = a0 + wid * 64;
    for (int i = 0; i < 64; ++i){
        int r = rbase + i;
        if (r >= A) break;                       // wave-uniform
        size_t idx = (size_t)b * A + r;
        const float* row = outputs + idx * (size_t)(C + 5);
        float x1 = row[lane];                    // elements 0..63 (coalesced)
        float x2 = (lane < 21) ? row[64 + lane] : 0.0f;  // elements 64..84

        float x4 = __shfl(x1, 4);
        float so = __builtin_amdgcn_rcpf(1.0f + __builtin_amdgcn_exp2f(-x4 * LOG2E_F));

        float s1c = 0.0f, b0c = 0.0f;
        if (lane >= 5){                          // classes 0..58
            float u = __builtin_amdgcn_exp2f(-x1 * LOG2E_F);
            float tden = 1.0f + u;
            float sig = __builtin_amdgcn_rcpf(tden);
            float p = __builtin_amdgcn_sqrtf(sig * so);
            s1c = fmaxf(LN2_F * __builtin_amdgcn_logf(1.0f - p), -100.0f);
            b0c = x1 + LN2_F * __builtin_amdgcn_logf(tden);
        }
        if (lane < 21){                          // classes 59..79
            float u = __builtin_amdgcn_exp2f(-x2 * LOG2E_F);
            float tden = 1.0f + u;
            float sig = __builtin_amdgcn_rcpf(tden);
            float p = __builtin_amdgcn_sqrtf(sig * so);
            s1c += fmaxf(LN2_F * __builtin_amdgcn_logf(1.0f - p), -100.0f);
            b0c += x2 + LN2_F * __builtin_amdgcn_logf(tden);
        }
#pragma unroll
        for (int off = 32; off; off >>= 1){
            s1c += __shfl_xor(s1c, off);
            b0c += __shfl_xor(b0c, off);
        }
        float bx = __shfl(x1, 0), by_ = __shfl(x1, 1);
        float bw_ = __shfl(x1, 2), bh_ = __shfl(x1, 3);
        if (lane == 0){
            S1mp[idx] = s1c; bce0[idx] = b0c; sobj[idx] = so; obj4[idx] = x4;
            bb4[idx] = make_float4(bx, by_, bw_, bh_);
        }
    }
    __syncthreads();   // slab ready + phase A done

    // ---- phase B: per-thread anchor work ----
    int a = a0 + t;
    if (a >= A) return;
    size_t idx = (size_t)b * A + a;

    float s = st[a];
    float xcv = (xs[a] + 0.5f) * s;
    float ycv = (ys[a] + 0.5f) * s;
    float rad = 2.5f * s;
    if (b == 0) anc4[a] = make_float4(xcv, ycv, rad, 0.0f);

    amg[idx] = 0; firstm[idx] = 0xFFFFFFFFu;

    bool any = false;
    for (int m = 0; m < M && !any; m++){
        const float* lab = (m < Ms) ? (slab + m * 5)
                                    : (labels + ((size_t)b * M + m) * 5);
        float gx = lab[0], gy = lab[1], gw = lab[2], gh = lab[3], g4v = lab[4];
        if (!((gx + gy + gw + gh + g4v) > 0.0f)) continue;   // valid
        bool inb = (xcv > gx - 0.5f * gw) && (gx + 0.5f * gw > xcv) &&
                   (ycv > gy - 0.5f * gh) && (gy + 0.5f * gh > ycv);
        bool inc = (xcv > gx - rad) && (xcv < gx + rad) &&
                   (ycv > gy - rad) && (ycv < gy + rad);
        any = inb || inc;
    }
    fgbuf[idx] = any ? 1 : 0;
}

// ---------------- kernel 1b: ordered fg compaction (1 block per image) ----------------
__global__ __launch_bounds__(TPB) void compact_kernel(
    const unsigned char* __restrict__ fgbuf, const float4* __restrict__ bb4,
    const float4* __restrict__ anc4, const float* __restrict__ S1mp,
    const float* __restrict__ sobj,
    float4* __restrict__ bbc, float4* __restrict__ ancc,
    float* __restrict__ sobc, int* __restrict__ aidxc, int* __restrict__ fgcnt,
    int A, int B)
{
    int b = blockIdx.x;
    int t = threadIdx.x;
    int lane = t & 63, wid = t >> 6;
    size_t base = (size_t)b * A;
    __shared__ int wtot[4];
    __shared__ int running;
    if (t == 0) running = 0;
    __syncthreads();
    for (int c0 = 0; c0 < A; c0 += TPB){
        int a = c0 + t;
        bool flag = (a < A) && (fgbuf[base + a] != 0);
        unsigned long long mask = __ballot(flag);
        int prefix = __popcll(mask & ((1ull << lane) - 1ull));
        int tot = __popcll(mask);
        if (lane == 0) wtot[wid] = tot;
        __syncthreads();
        int off = running;
        for (int w = 0; w < wid; w++) off += wtot[w];
        if (flag){
            int pos = off + prefix;
            bbc[base + pos] = bb4[base + a];
            float4 an = anc4[a];
            an.w = S1mp[base + a];
            ancc[base + pos] = an;
            sobc[base + pos] = sobj[base + a];
            aidxc[base + pos] = a;
        }
        __syncthreads();
        if (t == 0) running += wtot[0] + wtot[1] + wtot[2] + wtot[3];
        __syncthreads();
    }
    if (t == 0) fgcnt[b] = running;
}

// ---------------- kernel 2: per-GT SimOTA assignment over compacted fg set ----
__global__ __launch_bounds__(TPB) void assign_kernel(
    const float* __restrict__ outputs,
    const float* __restrict__ labels,
    const float4* __restrict__ bbc, const float4* __restrict__ ancc,
    const float* __restrict__ sobc, const int* __restrict__ aidxc,
    const int* __restrict__ fgcnt,
    int* __restrict__ amg, unsigned int* __restrict__ firstm,
    int A, int M, int C, int B)
{
    int b = blockIdx.x / M;
    int m = blockIdx.x - b * M;
    int t = threadIdx.x;
    int lane = t & 63, wid = t >> 6;

    const float* lab = labels + ((size_t)b * M + m) * 5;
    float gx = lab[0], gy = lab[1], gw = lab[2], gh = lab[3], g4 = lab[4];
    int  gc = (int)g4;
    bool valid = (gx + gy + gw + gh + g4) > 0.0f;
    if (!valid) return;   // uniform for whole block

    const size_t base = (size_t)b * A;
    const float* outb = outputs + base * (size_t)(C + 5);
    int n = fgcnt[b];

    float gl = gx - 0.5f * gw, gr = gx + 0.5f * gw;
    float gt_ = gy - 0.5f * gh, gb_ = gy + 0.5f * gh;

    float tv[10];                 // top-10 ious, descending
    float cv[10]; int ci[10];     // bottom-10 costs (value, orig anchor), ascending
#pragma unroll
    for (int j = 0; j < 10; j++){ tv[j] = -2.0f; cv[j] = 4e9f; ci[j] = 0x7fffffff; }
    int nib = 0;

    // ---- fused pass over fg set: iou (topk) + cost for in_both only ----
    for (int i = t; i < n; i += TPB){
        float4 bb = bbc[base + i];
        float4 an = ancc[base + i];     // x=xcv y=ycv z=rad w=S1

        float v = iou_fn(gx, gy, gw, gh, bb.x, bb.y, bb.z, bb.w);
        if (v > tv[9]){
            tv[9] = v;
#pragma unroll
            for (int j = 9; j > 0; j--){
                if (tv[j] > tv[j-1]){ float tm = tv[j]; tv[j] = tv[j-1]; tv[j-1] = tm; }
            }
        }

        bool inb = (an.x > gl) && (gr > an.x) && (an.y > gt_) && (gb_ > an.y);
        bool inc = (an.x > gx - an.z) && (an.x < gx + an.z) &&
                   (an.y > gy - an.z) && (an.y < gy + an.z);
        if (inb && inc){
            nib++;
            int a = aidxc[base + i];
            float c = cost_eval(bb.x, bb.y, bb.z, bb.w,
                                outb[(size_t)a * (C + 5) + 5 + gc],
                                sobc[base + i], an.w,
                                an.x, an.y, an.z, gx, gy, gw, gh, true, true);
            if (c < cv[9] || (c == cv[9] && a < ci[9])){
                cv[9] = c; ci[9] = a;
#pragma unroll
                for (int j = 9; j > 0; j--){
                    if (cv[j] < cv[j-1] || (cv[j] == cv[j-1] && ci[j] < ci[j-1])){
                        float tf = cv[j]; cv[j] = cv[j-1]; cv[j-1] = tf;
                        int  ti = ci[j]; ci[j] = ci[j-1]; ci[j-1] = ti;
                    }
                }
            }
        }
    }

    // ---- block-total #in_both ----
    __shared__ int snib[4];
    int nr = nib;
#pragma unroll
    for (int off = 32; off; off >>= 1) nr += __shfl_xor(nr, off);
    if (lane == 0) snib[wid] = nr;
    __syncthreads();
    int total_nib = snib[0] + snib[1] + snib[2] + snib[3];

    __shared__ float swv[2][4];
    __shared__ int   swi[2][4];

    // ---- top-10 iou sum, descending extraction (== lax.top_k order) ----
    float topsum = 0.0f;
    for (int k = 0; k < 10; k++){
        float v = tv[0];
        int who = t;
#pragma unroll
        for (int off = 32; off; off >>= 1){
            float v2 = __shfl_xor(v, off);
            int   w2 = __shfl_xor(who, off);
            if (v2 > v || (v2 == v && w2 < who)){ v = v2; who = w2; }
        }
        int slot = k & 1;
        if (lane == 0){ swv[slot][wid] = v; swi[slot][wid] = who; }
        __syncthreads();
        float gv = swv[slot][0]; int gwho = swi[slot][0];
#pragma unroll
        for (int w = 1; w < 4; w++){
            float v2 = swv[slot][w]; int w2 = swi[slot][w];
            if (v2 > gv || (v2 == gv && w2 < gwho)){ gv = v2; gwho = w2; }
        }
        topsum += fmaxf(gv, 0.0f);   // non-fg anchors are exact zeros in reference
        if (t == gwho){
#pragma unroll
            for (int j = 0; j < 9; j++) tv[j] = tv[j+1];
            tv[9] = -2.0f;
        }
    }
    int dyn_k = (int)topsum;
    if (dyn_k < 1) dyn_k = 1;
    if (dyn_k > 10) dyn_k = 10;

    // ---- rare fallback: not enough in_both anchors -> rescan all fg anchors ----
    if (dyn_k > total_nib){             // block-uniform condition
#pragma unroll
        for (int j = 0; j < 10; j++){ cv[j] = 4e9f; ci[j] = 0x7fffffff; }
        for (int i = t; i < n; i += TPB){
            float4 bb = bbc[base + i];
            float4 an = ancc[base + i];
            int a = aidxc[base + i];
            float c = cost_eval(bb.x, bb.y, bb.z, bb.w,
                                outb[(size_t)a * (C + 5) + 5 + gc],
                                sobc[base + i], an.w,
                                an.x, an.y, an.z, gx, gy, gw, gh, true, true);
            if (c < cv[9] || (c == cv[9] && a < ci[9])){
                cv[9] = c; ci[9] = a;
#pragma unroll
                for (int j = 9; j > 0; j--){
                    if (cv[j] < cv[j-1] || (cv[j] == cv[j-1] && ci[j] < ci[j-1])){
                        float tf = cv[j]; cv[j] = cv[j-1]; cv[j-1] = tf;
                        int  ti = ci[j]; ci[j] = ci[j-1]; ci[j-1] = ti;
                    }
                }
            }
        }
    }
    __syncthreads();

    // ---- select dyn_k smallest costs, stable (value, index) order ----
    for (int k = 0; k < dyn_k; k++){
        float v = cv[0]; int ai = ci[0];
#pragma unroll
        for (int off = 32; off; off >>= 1){
            float v2 = __shfl_xor(v, off);
            int   a2 = __shfl_xor(ai, off);
            if (v2 < v || (v2 == v && a2 < ai)){ v = v2; ai = a2; }
        }
        int slot = k & 1;
        if (lane == 0){ swv[slot][wid] = v; swi[slot][wid] = ai; }
        __syncthreads();
        float gv = swv[slot][0]; int gai = swi[slot][0];
#pragma unroll
        for (int w = 1; w < 4; w++){
            float v2 = swv[slot][w]; int a2 = swi[slot][w];
            if (v2 < gv || (v2 == gv && a2 < gai)){ gv = v2; gai = a2; }
        }
        if (gv >= 1e8f) break;          // only BIG left (fg set exhausted)
        if (cv[0] == gv && ci[0] == gai){   // unique winner thread
            atomicAdd(&amg[base + gai], 1);
            atomicMin(&firstm[base + gai], (unsigned)m);
#pragma unroll
            for (int j = 0; j < 9; j++){ cv[j] = cv[j+1]; ci[j] = ci[j+1]; }
            cv[9] = 4e9f; ci[9] = 0x7fffffff;
        }
    }
}

// ---------------- kernel 3: conflict resolution + loss (block partials) ----------------
__global__ __launch_bounds__(TPB) void finalize_kernel(
    const float* __restrict__ outputs,
    const float4* __restrict__ anc4,
    const float* __restrict__ labels, const float* __restrict__ S1mp,
    const float* __restrict__ sobj, const float* __restrict__ obj4,
    const float* __restrict__ bce0, const float4* __restrict__ bb4,
    const int* __restrict__ amg, const unsigned int* __restrict__ firstm,
    float* __restrict__ pacc, int A, int M, int C, int B)
{
    int idx = blockIdx.x * TPB + threadIdx.x;
    int BA = B * A;
    float s_iou = 0.0f, s_obj = 0.0f, s_cls = 0.0f, s_nfg = 0.0f;
    if (idx < BA){
        int b = idx / A;
        int a = idx - b * A;
        int cnt = amg[idx];
        bool fgf = cnt >= 1;
        s_obj = bce_fast(obj4[idx], fgf ? 1.0f : 0.0f);
        if (fgf){
            float4 bb = bb4[idx];
            int mgt = (int)firstm[idx];
            if (cnt > 1){
                // jnp.argmin(cost[:, a]) — first minimum; identical cost fn
                float S1 = S1mp[idx], so = sobj[idx];
                float4 an = anc4[a];
                const float* orow = outputs + (size_t)idx * (C + 5);
                float best = 1e30f; int bi = 0;
                for (int m = 0; m < M; m++){
                    const float* lab = labels + ((size_t)b * M + m) * 5;
                    float gx = lab[0], gy = lab[1], gw = lab[2], gh = lab[3], g4 = lab[4];
                    bool vld = (gx + gy + gw + gh + g4) > 0.0f;
                    float c = cost_eval(bb.x, bb.y, bb.z, bb.w, orow[5 + (int)g4],
                                        so, S1, an.x, an.y, an.z,
                                        gx, gy, gw, gh, vld, true);
                    if (c < best){ best = c; bi = m; }
                }
                mgt = bi;
            }
            const float* lab = labels + ((size_t)b * M + mgt) * 5;
            float pious = iou_fn(lab[0], lab[1], lab[2], lab[3], bb.x, bb.y, bb.z, bb.w);
            s_iou = 1.0f - pious * pious;
            s_nfg = 1.0f;
            int gc = (int)lab[4];
            // sum_c bce(x_c, pious*onehot) = sum_c bce(x_c,0) - x_gc*pious
            s_cls = bce0[idx] - outputs[(size_t)idx * (C + 5) + 5 + gc] * pious;
        }
    }
    // wave64 shuffle reduction -> LDS -> one 4-float partial per block (NO atomics)
    for (int off = 32; off > 0; off >>= 1){
        s_iou += __shfl_down(s_iou, off);
        s_obj += __shfl_down(s_obj, off);
        s_cls += __shfl_down(s_cls, off);
        s_nfg += __shfl_down(s_nfg, off);
    }
    __shared__ float red[4][4];   // [wave][scalar]
    int lane = threadIdx.x & 63, wid = threadIdx.x >> 6;
    if (lane == 0){
        red[wid][0] = s_iou; red[wid][1] = s_obj;
        red[wid][2] = s_cls; red[wid][3] = s_nfg;
    }
    __syncthreads();
    if (threadIdx.x < 4){
        float v = red[0][threadIdx.x] + red[1][threadIdx.x]
                + red[2][threadIdx.x] + red[3][threadIdx.x];
        pacc[(size_t)blockIdx.x * 4 + threadIdx.x] = v;
    }
}

// ---------------- kernel 4: reduce block partials -> final loss ----------------
__global__ __launch_bounds__(TPB) void combine_kernel(
    const float* __restrict__ pacc, int nblk, float* __restrict__ out)
{
    float s0 = 0.0f, s1 = 0.0f, s2 = 0.0f, s3 = 0.0f;
    for (int i = threadIdx.x; i < nblk; i += TPB){
        s0 += pacc[(size_t)i * 4 + 0];
        s1 += pacc[(size_t)i * 4 + 1];
        s2 += pacc[(size_t)i * 4 + 2];
        s3 += pacc[(size_t)i * 4 + 3];
    }
    for (int off = 32; off > 0; off >>= 1){
        s0 += __shfl_down(s0, off);
        s1 += __shfl_down(s1, off);
        s2 += __shfl_down(s2, off);
        s3 += __shfl_down(s3, off);
    }
    __shared__ float red[4][4];
    int lane = threadIdx.x & 63, wid = threadIdx.x >> 6;
    if (lane == 0){ red[wid][0] = s0; red[wid][1] = s1; red[wid][2] = s2; red[wid][3] = s3; }
    __syncthreads();
    if (threadIdx.x == 0){
        float t0 = red[0][0] + red[1][0] + red[2][0] + red[3][0];
        float t1 = red[0][1] + red[1][1] + red[2][1] + red[3][1];
        float t2 = red[0][2] + red[1][2] + red[2][2] + red[3][2];
        float t3 = red[0][3] + red[1][3] + red[2][3] + red[3][3];
        float nfg = fmaxf(t3, 1.0f);
        out[0] = (5.0f * t0 + t1 + t2) / nfg;
    }
}

extern "C" void kernel_launch(void* const* d_in, const int* in_sizes, int n_in,
                              void* d_out, int out_size, void* d_ws, size_t ws_size,
                              hipStream_t stream)
{
    const float* outputs = (const float*)d_in[0];
    const float* xs      = (const float*)d_in[1];
    const float* ys      = (const float*)d_in[2];
    const float* st      = (const float*)d_in[3];
    const float* labels  = (const float*)d_in[4];

    const int C = 80;                       // fixed benchmark
    int A = in_sizes[1];
    int B = in_sizes[0] / (A * (C + 5));
    int M = in_sizes[4] / (B * 5);
    int BA = B * A;
    int nb  = (BA + TPB - 1) / TPB;
    int nbA = (A + TPB - 1) / TPB;

    // workspace carve-up (256B aligned), ~23 MB total
    char* w = (char*)d_ws;
    auto carve = [&](size_t bytes) -> char* {
        char* p = w;
        w += (bytes + 255) & ~(size_t)255;
        return p;
    };
    float* S1mp = (float*)carve((size_t)BA * 4);
    float* sobj = (float*)carve((size_t)BA * 4);
    float* obj4 = (float*)carve((size_t)BA * 4);
    float* bce0 = (float*)carve((size_t)BA * 4);
    float4* bb4 = (float4*)carve((size_t)BA * 16);
    int*   amg  = (int*)carve((size_t)BA * 4);
    unsigned int* firstm = (unsigned int*)carve((size_t)BA * 4);
    unsigned char* fgbuf = (unsigned char*)carve((size_t)BA);
    float4* anc4 = (float4*)carve((size_t)A * 16);
    float* pacc = (float*)carve((size_t)nb * 4 * 4);
    // compacted fg arrays
    float4* bbc  = (float4*)carve((size_t)BA * 16);
    float4* ancc = (float4*)carve((size_t)BA * 16);
    float*  sobc = (float*)carve((size_t)BA * 4);
    int*    aidxc= (int*)carve((size_t)BA * 4);
    int*    fgcnt= (int*)carve((size_t)B * 4);

    precompute_kernel<<<dim3(B * nbA), dim3(TPB), 0, stream>>>(
        outputs, xs, ys, st, labels, S1mp, sobj, obj4, bce0,
        bb4, fgbuf, amg, firstm, anc4, A, M, C, B, nbA);
    compact_kernel<<<dim3(B), dim3(TPB), 0, stream>>>(
        fgbuf, bb4, anc4, S1mp, sobj, bbc, ancc, sobc, aidxc, fgcnt, A, B);
    assign_kernel<<<dim3(B * M), dim3(TPB), 0, stream>>>(
        outputs, labels, bbc, ancc, sobc, aidxc, fgcnt,
        amg, firstm, A, M, C, B);
    finalize_kernel<<<dim3(nb), dim3(TPB), 0, stream>>>(
        outputs, anc4, labels, S1mp, sobj, obj4, bce0,
        bb4, amg, firstm, pacc, A, M, C, B);
    combine_kernel<<<dim3(1), dim3(TPB), 0, stream>>>(pacc, nb, (float*)d_out);
}

// Round 9
// 278.006 us; speedup vs baseline: 1.2428x; 1.2428x over previous
//
#include <hip/hip_runtime.h>
#include <math.h>

#define TPB 256

#define LOG2E_F 1.4426950408889634f
#define LN2_F   0.6931471805599453f

__device__ __forceinline__ float sigmoidf_(float x){
    return 1.0f / (1.0f + expf(-x));
}

// HW-transcendental BCE (continuous loss path only)
__device__ __forceinline__ float bce_fast(float x, float t){
    float u = __builtin_amdgcn_exp2f(-fabsf(x) * LOG2E_F);
    return fmaxf(x, 0.0f) - x * t + LN2_F * __builtin_amdgcn_logf(1.0f + u);
}

// IoU between box a (cx,cy,w,h) and box b (cx,cy,w,h) — mirrors _pairwise_iou.
__device__ float iou_fn(float ax, float ay, float aw, float ah,
                        float bx, float by, float bw, float bh){
#pragma clang fp contract(off)
    float tlx = fmaxf(ax - aw * 0.5f, bx - bw * 0.5f);
    float tly = fmaxf(ay - ah * 0.5f, by - bh * 0.5f);
    float brx = fminf(ax + aw * 0.5f, bx + bw * 0.5f);
    float bry = fminf(ay + ah * 0.5f, by + bh * 0.5f);
    float area_a = aw * ah;
    float area_b = bw * bh;
    bool  en = (tlx < brx) && (tly < bry);
    float area_i = en ? (brx - tlx) * (bry - tly) : 0.0f;
    return area_i / (area_a + area_b - area_i + 1e-16f);
}

// Full cost(m, a). MUST be bitwise-identical between assign (selection) and
// finalize (argmin conflict resolution) — hence contract(off) and shared code.
__device__ float cost_eval(float ox, float oy, float ow, float oh,
                           float clslogit, float so, float S1,
                           float xcv, float ycv, float rad,
                           float gx, float gy, float gw, float gh,
                           bool valid, bool fgflag){
#pragma clang fp contract(off)
    if (!(valid && fgflag)) return 1e9f;   // BIG
    float raw = iou_fn(gx, gy, gw, gh, ox, oy, ow, oh);
    bool inb = (xcv > gx - 0.5f * gw) && (gx + 0.5f * gw > xcv) &&
               (ycv > gy - 0.5f * gh) && (gy + 0.5f * gh > ycv);
    bool inc = (xcv > gx - rad) && (xcv < gx + rad) &&
               (ycv > gy - rad) && (ycv < gy + rad);
    bool in_both = inb && inc;
    float pt = sqrtf(sigmoidf_(clslogit) * so);
    float logp = fmaxf(logf(pt), -100.0f);
    float l1mp = fmaxf(log1pf(-pt), -100.0f);
    float cls_cost = -(logp + S1 - l1mp);
    return cls_cost + 3.0f * (-logf(raw + 1e-8f)) + (in_both ? 0.0f : 100000.0f);
}

// ---------------- kernel 1: per-anchor precompute ----------------
// Phase A: 4 sub-tiles of 64 rows staged in LDS (coalesced float4); 256
// threads = 64 rows x 4 quad-lanes; each lane does 20 classes (independent
// VALU chain, HW transcendentals); reduce = 2 shfl_xor levels within quad.
// Phase B: per-thread anchor geometry + fg M-scan + per-chunk fg count.
__global__ __launch_bounds__(TPB) void precompute_kernel(
    const float* __restrict__ outputs, const float* __restrict__ xs,
    const float* __restrict__ ys, const float* __restrict__ st,
    const float* __restrict__ labels,
    float* __restrict__ S1mp, float* __restrict__ sobj, float* __restrict__ obj4,
    float* __restrict__ bce0, float4* __restrict__ bb4,
    unsigned char* __restrict__ fgbuf,
    int* __restrict__ amg, unsigned int* __restrict__ firstm,
    float4* __restrict__ anc4, int* __restrict__ chunkcnt,
    int A, int M, int C, int B, int nbA)
{
    __shared__ float tile[64 * 85];   // 21,760 B
    __shared__ float slab[64 * 5];
    __shared__ int wtot[4];
    int t = threadIdx.x;
    int b = blockIdx.x / nbA;
    int chunk = blockIdx.x - b * nbA;
    int a0 = chunk * TPB;
    int Ms = M < 64 ? M : 64;
    for (int i = t; i < Ms * 5; i += TPB) slab[i] = labels[(size_t)b * M * 5 + i];

    int row = t >> 2, q = t & 3;
    // ---- phase A: 4 sub-tiles of 64 rows ----
    for (int s = 0; s < 4; ++s){
        int r0 = a0 + s * 64;                    // block-uniform
        int nrows = A - r0; if (nrows > 64) nrows = 64;
        if (nrows <= 0) break;                   // uniform
        int nf = nrows * 85;
        const float* g = outputs + ((size_t)b * A + r0) * 85;
        if ((((size_t)g) & 15) == 0){
            int n4 = nf >> 2;
            const float4* g4 = (const float4*)g;
            float4* l4 = (float4*)tile;
            for (int i = t; i < n4; i += TPB) l4[i] = g4[i];
            for (int i = (n4 << 2) + t; i < nf; i += TPB) tile[i] = g[i];
        } else {
            for (int i = t; i < nf; i += TPB) tile[i] = g[i];
        }
        __syncthreads();
        if (row < nrows){
            const float* rw = tile + row * 85;
            size_t idx = (size_t)b * A + r0 + row;
            float x4 = rw[4];
            float so = __builtin_amdgcn_rcpf(1.0f + __builtin_amdgcn_exp2f(-x4 * LOG2E_F));
            float s1c = 0.0f, b0c = 0.0f;
            const float* cls = rw + 5 + q * 20;
#pragma unroll 5
            for (int k = 0; k < 20; ++k){
                float xc = cls[k];
                float u = __builtin_amdgcn_exp2f(-xc * LOG2E_F);
                float tden = 1.0f + u;
                float sig = __builtin_amdgcn_rcpf(tden);
                float p = __builtin_amdgcn_sqrtf(sig * so);
                s1c += fmaxf(LN2_F * __builtin_amdgcn_logf(1.0f - p), -100.0f);
                b0c += xc + LN2_F * __builtin_amdgcn_logf(tden);
            }
            s1c += __shfl_xor(s1c, 1); s1c += __shfl_xor(s1c, 2);
            b0c += __shfl_xor(b0c, 1); b0c += __shfl_xor(b0c, 2);
            if (q == 0){
                S1mp[idx] = s1c; bce0[idx] = b0c; sobj[idx] = so; obj4[idx] = x4;
                bb4[idx] = make_float4(rw[0], rw[1], rw[2], rw[3]);
            }
        }
        __syncthreads();
    }

    // ---- phase B: per-thread anchor work + chunk fg count ----
    int a = a0 + t;
    int lane = t & 63, wid = t >> 6;
    bool flag = false;
    if (a < A){
        size_t idx = (size_t)b * A + a;
        float s = st[a];
        float xcv = (xs[a] + 0.5f) * s;
        float ycv = (ys[a] + 0.5f) * s;
        float rad = 2.5f * s;
        if (b == 0) anc4[a] = make_float4(xcv, ycv, rad, 0.0f);
        amg[idx] = 0; firstm[idx] = 0xFFFFFFFFu;

        bool any = false;
        for (int m = 0; m < M && !any; m++){
            const float* lab = (m < Ms) ? (slab + m * 5)
                                        : (labels + ((size_t)b * M + m) * 5);
            float gx = lab[0], gy = lab[1], gw = lab[2], gh = lab[3], g4v = lab[4];
            if (!((gx + gy + gw + gh + g4v) > 0.0f)) continue;   // valid
            bool inb = (xcv > gx - 0.5f * gw) && (gx + 0.5f * gw > xcv) &&
                       (ycv > gy - 0.5f * gh) && (gy + 0.5f * gh > ycv);
            bool inc = (xcv > gx - rad) && (xcv < gx + rad) &&
                       (ycv > gy - rad) && (ycv < gy + rad);
            any = inb || inc;
        }
        fgbuf[idx] = any ? 1 : 0;
        flag = any;
    }
    unsigned long long mask = __ballot(flag);
    if (lane == 0) wtot[wid] = __popcll(mask);
    __syncthreads();
    if (t == 0) chunkcnt[b * nbA + chunk] = wtot[0] + wtot[1] + wtot[2] + wtot[3];
}

// ---------------- kernel 1b: per-image chunk-offset scan (tiny) ----------------
__global__ __launch_bounds__(64) void scan_kernel(
    const int* __restrict__ chunkcnt, int* __restrict__ chunkoff,
    int* __restrict__ fgcnt, int B, int nbA)
{
    int b = threadIdx.x + blockIdx.x * 64;
    if (b >= B) return;
    int run = 0;
    for (int c = 0; c < nbA; c++){
        chunkoff[b * nbA + c] = run;
        run += chunkcnt[b * nbA + c];
    }
    fgcnt[b] = run;
}

// ---------------- kernel 1c: parallel ordered scatter ----------------
// Same ascending-anchor compact order as the old serial compaction.
__global__ __launch_bounds__(TPB) void scatter_kernel(
    const unsigned char* __restrict__ fgbuf, const float4* __restrict__ bb4,
    const float4* __restrict__ anc4, const float* __restrict__ S1mp,
    const float* __restrict__ sobj, const int* __restrict__ chunkoff,
    float4* __restrict__ bbc, float4* __restrict__ ancc,
    float* __restrict__ sobc, int* __restrict__ aidxc,
    int A, int nbA)
{
    int t = threadIdx.x;
    int b = blockIdx.x / nbA;
    int chunk = blockIdx.x - b * nbA;
    int a = chunk * TPB + t;
    size_t base = (size_t)b * A;
    bool flag = (a < A) && (fgbuf[base + a] != 0);
    int lane = t & 63, wid = t >> 6;
    unsigned long long mask = __ballot(flag);
    int prefix = __popcll(mask & ((1ull << lane) - 1ull));
    __shared__ int wtot[4];
    if (lane == 0) wtot[wid] = __popcll(mask);
    __syncthreads();
    int off = chunkoff[b * nbA + chunk];
    for (int w = 0; w < wid; w++) off += wtot[w];
    if (flag){
        int pos = off + prefix;
        bbc[base + pos] = bb4[base + a];
        float4 an = anc4[a];
        an.w = S1mp[base + a];
        ancc[base + pos] = an;
        sobc[base + pos] = sobj[base + a];
        aidxc[base + pos] = a;
    }
}

// ---------------- kernel 2: per-GT SimOTA assignment over compacted fg set ----
__global__ __launch_bounds__(TPB) void assign_kernel(
    const float* __restrict__ outputs,
    const float* __restrict__ labels,
    const float4* __restrict__ bbc, const float4* __restrict__ ancc,
    const float* __restrict__ sobc, const int* __restrict__ aidxc,
    const int* __restrict__ fgcnt,
    int* __restrict__ amg, unsigned int* __restrict__ firstm,
    int A, int M, int C, int B)
{
    int b = blockIdx.x / M;
    int m = blockIdx.x - b * M;
    int t = threadIdx.x;
    int lane = t & 63, wid = t >> 6;

    const float* lab = labels + ((size_t)b * M + m) * 5;
    float gx = lab[0], gy = lab[1], gw = lab[2], gh = lab[3], g4 = lab[4];
    int  gc = (int)g4;
    bool valid = (gx + gy + gw + gh + g4) > 0.0f;
    if (!valid) return;   // uniform for whole block

    const size_t base = (size_t)b * A;
    const float* outb = outputs + base * (size_t)(C + 5);
    int n = fgcnt[b];

    float gl = gx - 0.5f * gw, gr = gx + 0.5f * gw;
    float gt_ = gy - 0.5f * gh, gb_ = gy + 0.5f * gh;

    float tv[10];                 // top-10 ious, descending
    float cv[10]; int ci[10];     // bottom-10 costs (value, orig anchor), ascending
#pragma unroll
    for (int j = 0; j < 10; j++){ tv[j] = -2.0f; cv[j] = 4e9f; ci[j] = 0x7fffffff; }
    int nib = 0;

    // ---- fused pass over fg set: iou (topk) + cost for in_both only ----
    for (int i = t; i < n; i += TPB){
        float4 bb = bbc[base + i];
        float4 an = ancc[base + i];     // x=xcv y=ycv z=rad w=S1

        float v = iou_fn(gx, gy, gw, gh, bb.x, bb.y, bb.z, bb.w);
        if (v > tv[9]){
            tv[9] = v;
#pragma unroll
            for (int j = 9; j > 0; j--){
                if (tv[j] > tv[j-1]){ float tm = tv[j]; tv[j] = tv[j-1]; tv[j-1] = tm; }
            }
        }

        bool inb = (an.x > gl) && (gr > an.x) && (an.y > gt_) && (gb_ > an.y);
        bool inc = (an.x > gx - an.z) && (an.x < gx + an.z) &&
                   (an.y > gy - an.z) && (an.y < gy + an.z);
        if (inb && inc){
            nib++;
            int a = aidxc[base + i];
            float c = cost_eval(bb.x, bb.y, bb.z, bb.w,
                                outb[(size_t)a * (C + 5) + 5 + gc],
                                sobc[base + i], an.w,
                                an.x, an.y, an.z, gx, gy, gw, gh, true, true);
            if (c < cv[9] || (c == cv[9] && a < ci[9])){
                cv[9] = c; ci[9] = a;
#pragma unroll
                for (int j = 9; j > 0; j--){
                    if (cv[j] < cv[j-1] || (cv[j] == cv[j-1] && ci[j] < ci[j-1])){
                        float tf = cv[j]; cv[j] = cv[j-1]; cv[j-1] = tf;
                        int  ti = ci[j]; ci[j] = ci[j-1]; ci[j-1] = ti;
                    }
                }
            }
        }
    }

    // ---- block-total #in_both ----
    __shared__ int snib[4];
    int nr = nib;
#pragma unroll
    for (int off = 32; off; off >>= 1) nr += __shfl_xor(nr, off);
    if (lane == 0) snib[wid] = nr;
    __syncthreads();
    int total_nib = snib[0] + snib[1] + snib[2] + snib[3];

    __shared__ float swv[2][4];
    __shared__ int   swi[2][4];

    // ---- top-10 iou sum, descending extraction (== lax.top_k order) ----
    float topsum = 0.0f;
    for (int k = 0; k < 10; k++){
        float v = tv[0];
        int who = t;
#pragma unroll
        for (int off = 32; off; off >>= 1){
            float v2 = __shfl_xor(v, off);
            int   w2 = __shfl_xor(who, off);
            if (v2 > v || (v2 == v && w2 < who)){ v = v2; who = w2; }
        }
        int slot = k & 1;
        if (lane == 0){ swv[slot][wid] = v; swi[slot][wid] = who; }
        __syncthreads();
        float gv = swv[slot][0]; int gwho = swi[slot][0];
#pragma unroll
        for (int w = 1; w < 4; w++){
            float v2 = swv[slot][w]; int w2 = swi[slot][w];
            if (v2 > gv || (v2 == gv && w2 < gwho)){ gv = v2; gwho = w2; }
        }
        topsum += fmaxf(gv, 0.0f);   // non-fg anchors are exact zeros in reference
        if (t == gwho){
#pragma unroll
            for (int j = 0; j < 9; j++) tv[j] = tv[j+1];
            tv[9] = -2.0f;
        }
    }
    int dyn_k = (int)topsum;
    if (dyn_k < 1) dyn_k = 1;
    if (dyn_k > 10) dyn_k = 10;

    // ---- rare fallback: not enough in_both anchors -> rescan all fg anchors ----
    if (dyn_k > total_nib){             // block-uniform condition
#pragma unroll
        for (int j = 0; j < 10; j++){ cv[j] = 4e9f; ci[j] = 0x7fffffff; }
        for (int i = t; i < n; i += TPB){
            float4 bb = bbc[base + i];
            float4 an = ancc[base + i];
            int a = aidxc[base + i];
            float c = cost_eval(bb.x, bb.y, bb.z, bb.w,
                                outb[(size_t)a * (C + 5) + 5 + gc],
                                sobc[base + i], an.w,
                                an.x, an.y, an.z, gx, gy, gw, gh, true, true);
            if (c < cv[9] || (c == cv[9] && a < ci[9])){
                cv[9] = c; ci[9] = a;
#pragma unroll
                for (int j = 9; j > 0; j--){
                    if (cv[j] < cv[j-1] || (cv[j] == cv[j-1] && ci[j] < ci[j-1])){
                        float tf = cv[j]; cv[j] = cv[j-1]; cv[j-1] = tf;
                        int  ti = ci[j]; ci[j] = ci[j-1]; ci[j-1] = ti;
                    }
                }
            }
        }
    }
    __syncthreads();

    // ---- select dyn_k smallest costs, stable (value, index) order ----
    for (int k = 0; k < dyn_k; k++){
        float v = cv[0]; int ai = ci[0];
#pragma unroll
        for (int off = 32; off; off >>= 1){
            float v2 = __shfl_xor(v, off);
            int   a2 = __shfl_xor(ai, off);
            if (v2 < v || (v2 == v && a2 < ai)){ v = v2; ai = a2; }
        }
        int slot = k & 1;
        if (lane == 0){ swv[slot][wid] = v; swi[slot][wid] = ai; }
        __syncthreads();
        float gv = swv[slot][0]; int gai = swi[slot][0];
#pragma unroll
        for (int w = 1; w < 4; w++){
            float v2 = swv[slot][w]; int a2 = swi[slot][w];
            if (v2 < gv || (v2 == gv && a2 < gai)){ gv = v2; gai = a2; }
        }
        if (gv >= 1e8f) break;          // only BIG left (fg set exhausted)
        if (cv[0] == gv && ci[0] == gai){   // unique winner thread
            atomicAdd(&amg[base + gai], 1);
            atomicMin(&firstm[base + gai], (unsigned)m);
#pragma unroll
            for (int j = 0; j < 9; j++){ cv[j] = cv[j+1]; ci[j] = ci[j+1]; }
            cv[9] = 4e9f; ci[9] = 0x7fffffff;
        }
    }
}

// ---------------- kernel 3: conflict resolution + loss (block partials) ----------------
__global__ __launch_bounds__(TPB) void finalize_kernel(
    const float* __restrict__ outputs,
    const float4* __restrict__ anc4,
    const float* __restrict__ labels, const float* __restrict__ S1mp,
    const float* __restrict__ sobj, const float* __restrict__ obj4,
    const float* __restrict__ bce0, const float4* __restrict__ bb4,
    const int* __restrict__ amg, const unsigned int* __restrict__ firstm,
    float* __restrict__ pacc, int A, int M, int C, int B)
{
    int idx = blockIdx.x * TPB + threadIdx.x;
    int BA = B * A;
    float s_iou = 0.0f, s_obj = 0.0f, s_cls = 0.0f, s_nfg = 0.0f;
    if (idx < BA){
        int b = idx / A;
        int a = idx - b * A;
        int cnt = amg[idx];
        bool fgf = cnt >= 1;
        s_obj = bce_fast(obj4[idx], fgf ? 1.0f : 0.0f);
        if (fgf){
            float4 bb = bb4[idx];
            int mgt = (int)firstm[idx];
            if (cnt > 1){
                // jnp.argmin(cost[:, a]) — first minimum; identical cost fn
                float S1 = S1mp[idx], so = sobj[idx];
                float4 an = anc4[a];
                const float* orow = outputs + (size_t)idx * (C + 5);
                float best = 1e30f; int bi = 0;
                for (int m = 0; m < M; m++){
                    const float* lab = labels + ((size_t)b * M + m) * 5;
                    float gx = lab[0], gy = lab[1], gw = lab[2], gh = lab[3], g4 = lab[4];
                    bool vld = (gx + gy + gw + gh + g4) > 0.0f;
                    float c = cost_eval(bb.x, bb.y, bb.z, bb.w, orow[5 + (int)g4],
                                        so, S1, an.x, an.y, an.z,
                                        gx, gy, gw, gh, vld, true);
                    if (c < best){ best = c; bi = m; }
                }
                mgt = bi;
            }
            const float* lab = labels + ((size_t)b * M + mgt) * 5;
            float pious = iou_fn(lab[0], lab[1], lab[2], lab[3], bb.x, bb.y, bb.z, bb.w);
            s_iou = 1.0f - pious * pious;
            s_nfg = 1.0f;
            int gc = (int)lab[4];
            // sum_c bce(x_c, pious*onehot) = sum_c bce(x_c,0) - x_gc*pious
            s_cls = bce0[idx] - outputs[(size_t)idx * (C + 5) + 5 + gc] * pious;
        }
    }
    // wave64 shuffle reduction -> LDS -> one 4-float partial per block (NO atomics)
    for (int off = 32; off > 0; off >>= 1){
        s_iou += __shfl_down(s_iou, off);
        s_obj += __shfl_down(s_obj, off);
        s_cls += __shfl_down(s_cls, off);
        s_nfg += __shfl_down(s_nfg, off);
    }
    __shared__ float red[4][4];   // [wave][scalar]
    int lane = threadIdx.x & 63, wid = threadIdx.x >> 6;
    if (lane == 0){
        red[wid][0] = s_iou; red[wid][1] = s_obj;
        red[wid][2] = s_cls; red[wid][3] = s_nfg;
    }
    __syncthreads();
    if (threadIdx.x < 4){
        float v = red[0][threadIdx.x] + red[1][threadIdx.x]
                + red[2][threadIdx.x] + red[3][threadIdx.x];
        pacc[(size_t)blockIdx.x * 4 + threadIdx.x] = v;
    }
}

// ---------------- kernel 4: reduce block partials -> final loss ----------------
__global__ __launch_bounds__(TPB) void combine_kernel(
    const float* __restrict__ pacc, int nblk, float* __restrict__ out)
{
    float s0 = 0.0f, s1 = 0.0f, s2 = 0.0f, s3 = 0.0f;
    for (int i = threadIdx.x; i < nblk; i += TPB){
        s0 += pacc[(size_t)i * 4 + 0];
        s1 += pacc[(size_t)i * 4 + 1];
        s2 += pacc[(size_t)i * 4 + 2];
        s3 += pacc[(size_t)i * 4 + 3];
    }
    for (int off = 32; off > 0; off >>= 1){
        s0 += __shfl_down(s0, off);
        s1 += __shfl_down(s1, off);
        s2 += __shfl_down(s2, off);
        s3 += __shfl_down(s3, off);
    }
    __shared__ float red[4][4];
    int lane = threadIdx.x & 63, wid = threadIdx.x >> 6;
    if (lane == 0){ red[wid][0] = s0; red[wid][1] = s1; red[wid][2] = s2; red[wid][3] = s3; }
    __syncthreads();
    if (threadIdx.x == 0){
        float t0 = red[0][0] + red[1][0] + red[2][0] + red[3][0];
        float t1 = red[0][1] + red[1][1] + red[2][1] + red[3][1];
        float t2 = red[0][2] + red[1][2] + red[2][2] + red[3][2];
        float t3 = red[0][3] + red[1][3] + red[2][3] + red[3][3];
        float nfg = fmaxf(t3, 1.0f);
        out[0] = (5.0f * t0 + t1 + t2) / nfg;
    }
}

extern "C" void kernel_launch(void* const* d_in, const int* in_sizes, int n_in,
                              void* d_out, int out_size, void* d_ws, size_t ws_size,
                              hipStream_t stream)
{
    const float* outputs = (const float*)d_in[0];
    const float* xs      = (const float*)d_in[1];
    const float* ys      = (const float*)d_in[2];
    const float* st      = (const float*)d_in[3];
    const float* labels  = (const float*)d_in[4];

    const int C = 80;                       // fixed benchmark
    int A = in_sizes[1];
    int B = in_sizes[0] / (A * (C + 5));
    int M = in_sizes[4] / (B * 5);
    int BA = B * A;
    int nb  = (BA + TPB - 1) / TPB;
    int nbA = (A + TPB - 1) / TPB;

    // workspace carve-up (256B aligned), ~23 MB total
    char* w = (char*)d_ws;
    auto carve = [&](size_t bytes) -> char* {
        char* p = w;
        w += (bytes + 255) & ~(size_t)255;
        return p;
    };
    float* S1mp = (float*)carve((size_t)BA * 4);
    float* sobj = (float*)carve((size_t)BA * 4);
    float* obj4 = (float*)carve((size_t)BA * 4);
    float* bce0 = (float*)carve((size_t)BA * 4);
    float4* bb4 = (float4*)carve((size_t)BA * 16);
    int*   amg  = (int*)carve((size_t)BA * 4);
    unsigned int* firstm = (unsigned int*)carve((size_t)BA * 4);
    unsigned char* fgbuf = (unsigned char*)carve((size_t)BA);
    float4* anc4 = (float4*)carve((size_t)A * 16);
    float* pacc = (float*)carve((size_t)nb * 4 * 4);
    // compacted fg arrays
    float4* bbc  = (float4*)carve((size_t)BA * 16);
    float4* ancc = (float4*)carve((size_t)BA * 16);
    float*  sobc = (float*)carve((size_t)BA * 4);
    int*    aidxc= (int*)carve((size_t)BA * 4);
    int*    fgcnt= (int*)carve((size_t)B * 4);
    int*    chunkcnt = (int*)carve((size_t)B * nbA * 4);
    int*    chunkoff = (int*)carve((size_t)B * nbA * 4);

    precompute_kernel<<<dim3(B * nbA), dim3(TPB), 0, stream>>>(
        outputs, xs, ys, st, labels, S1mp, sobj, obj4, bce0,
        bb4, fgbuf, amg, firstm, anc4, chunkcnt, A, M, C, B, nbA);
    scan_kernel<<<dim3((B + 63) / 64), dim3(64), 0, stream>>>(
        chunkcnt, chunkoff, fgcnt, B, nbA);
    scatter_kernel<<<dim3(B * nbA), dim3(TPB), 0, stream>>>(
        fgbuf, bb4, anc4, S1mp, sobj, chunkoff,
        bbc, ancc, sobc, aidxc, A, nbA);
    assign_kernel<<<dim3(B * M), dim3(TPB), 0, stream>>>(
        outputs, labels, bbc, ancc, sobc, aidxc, fgcnt,
        amg, firstm, A, M, C, B);
    finalize_kernel<<<dim3(nb), dim3(TPB), 0, stream>>>(
        outputs, anc4, labels, S1mp, sobj, obj4, bce0,
        bb4, amg, firstm, pacc, A, M, C, B);
    combine_kernel<<<dim3(1), dim3(TPB), 0, stream>>>(pacc, nb, (float*)d_out);
}